// Round 4
// baseline (197.633 us; speedup 1.0000x reference)
//
#include <hip/hip_runtime.h>

// B=4, H=W=32, C=256. 8 tasks (sample x orientation), grid L=992 each.
// Pipeline: Mh=f16(a*b) -> S = Mh Mh^T (MFMA, f16 out)
//   G[l1,l2] = sum_{d in 3x3} S[l1+d, l2+d] (9-pt, fused) -> softmax -> Ph
//   Wh[m,c]  = sum_{d in 3x3} Ph[m+d, c+d] (9-pt, same validity form)
//   Y = Wh @ ABt^T (MFMA f16, f32 out) -> seam combine.
// All grids are flat with t = blockIdx.x & 7 so each task's blocks land on
// one XCD (round-robin heuristic): per-task working sets (<=2MB) stay L2-hot.

typedef _Float16 half8 __attribute__((ext_vector_type(8)));
typedef _Float16 half4h __attribute__((ext_vector_type(4)));
typedef float floatx4 __attribute__((ext_vector_type(4)));

constexpr int NL = 992, NC = 256, NC2 = 512;
constexpr int NLL = NL * NL;
// float-granular per-task offsets
constexpr int OFF_S   = 0;                     // f16 LxL: S, later Wh (S dead after softmax)
constexpr int OFF_P   = NLL / 2;               // f16 LxL: Ph
constexpr int OFF_Y   = NLL;                   // f32 [992][512]
constexpr int OFF_ABT = OFF_Y + NL * NC2;      // f16 [512][992]
constexpr int OFF_MH  = OFF_ABT + NL * NC2 / 2;// f16 [992][256]
constexpr int OFF_SA  = OFF_MH + NL * NC / 2;
constexpr int OFF_SB  = OFF_SA + 1024;
constexpr int OFF_INV = OFF_SA + 2048;
constexpr int TSTRIDE = OFF_SA + 3072;         // 1,875,968 f -> 60 MB total

__device__ __forceinline__ void gload16(const void* g, void* l) {
    __builtin_amdgcn_global_load_lds(
        (const __attribute__((address_space(1))) unsigned int*)g,
        (__attribute__((address_space(3))) unsigned int*)(unsigned long)(uintptr_t)l,
        16, 0, 0);
}

// ---------------- K1: Mh = f16(a*b), per-pixel squared norms ----------------
__global__ __launch_bounds__(256) void k_prep(const float* __restrict__ x,
                                              float* __restrict__ ws) {
    const int t = blockIdx.x & 7;
    const int l = blockIdx.x >> 3;
    const int s = t >> 1, o = t & 1;
    int aoff, boff;
    if (o == 0) {  // lr grid (31,32)
        const int lh = l >> 5, lw = l & 31;
        aoff = ((s * 32 + lh) * 32 + lw) * NC;
        boff = ((s * 32 + lh + 1) * 32 + lw) * NC;
    } else {       // tb grid (32,31)
        const int lh = l / 31, lw = l - lh * 31;
        aoff = ((s * 32 + lh) * 32 + lw + 1) * NC;
        boff = ((s * 32 + lh) * 32 + lw) * NC;
    }
    float* wst = ws + (size_t)t * TSTRIDE;
    const int c = threadIdx.x;
    const float av = x[aoff + c];
    const float bv = x[boff + c];
    ((_Float16*)(wst + OFF_MH))[l * NC + c] = (_Float16)(av * bv);
    float ra = av * av, rb = bv * bv;
#pragma unroll
    for (int off = 32; off > 0; off >>= 1) {
        ra += __shfl_down(ra, off);
        rb += __shfl_down(rb, off);
    }
    __shared__ float shA[4], shB[4];
    const int wave = threadIdx.x >> 6, lane = threadIdx.x & 63;
    if (lane == 0) { shA[wave] = ra; shB[wave] = rb; }
    __syncthreads();
    if (threadIdx.x == 0) {
        wst[OFF_SA + l] = shA[0] + shA[1] + shA[2] + shA[3];
        wst[OFF_SB + l] = shB[0] + shB[1] + shB[2] + shB[3];
    }
}

// ---------------- K1b: ABt[c][l] (f16) via 32x32 LDS transpose ----------------
__global__ __launch_bounds__(256) void k_abt(const float* __restrict__ x,
                                             float* __restrict__ ws) {
    const int t = blockIdx.x & 7;
    const int u = blockIdx.x >> 3;    // 0..495 = 16 cblk x 31 lblk
    const int cbk = u / 31;
    const int c0 = cbk * 32;
    const int l0 = (u - cbk * 31) * 32;
    const int s = t >> 1, o = t & 1;
    float* wst = ws + (size_t)t * TSTRIDE;
    _Float16* __restrict__ ABt = (_Float16*)(wst + OFF_ABT);
    __shared__ float T[32 * 33];
    const int tid = threadIdx.x;
    const bool isB = (c0 >= 256);
    const int cb = isB ? c0 - 256 : c0;
    {
        const int li = tid >> 3, cq = tid & 7;
        const int l = l0 + li;
        int xoff;
        if (o == 0) {
            const int lh = l >> 5, lw = l & 31;
            xoff = isB ? ((s * 32 + lh + 1) * 32 + lw) : ((s * 32 + lh) * 32 + lw);
        } else {
            const int lh = l / 31, lw = l - lh * 31;
            xoff = isB ? ((s * 32 + lh) * 32 + lw) : ((s * 32 + lh) * 32 + lw + 1);
        }
        const float4 v = *(const float4*)&x[xoff * NC + cb + cq * 4];
        T[(cq * 4 + 0) * 33 + li] = v.x;
        T[(cq * 4 + 1) * 33 + li] = v.y;
        T[(cq * 4 + 2) * 33 + li] = v.z;
        T[(cq * 4 + 3) * 33 + li] = v.w;
    }
    __syncthreads();
    {
        const int ci = tid >> 3, lq = tid & 7;
        half4h h;
        h.x = (_Float16)T[ci * 33 + lq * 4 + 0];
        h.y = (_Float16)T[ci * 33 + lq * 4 + 1];
        h.z = (_Float16)T[ci * 33 + lq * 4 + 2];
        h.w = (_Float16)T[ci * 33 + lq * 4 + 3];
        *(half4h*)&ABt[(c0 + ci) * NL + l0 + lq * 4] = h;
    }
}

// ---------------- K2: inv from 3x3 box sums of squared norms ----------------
__global__ __launch_bounds__(1024) void k_inv(float* __restrict__ ws) {
    const int t = blockIdx.x;
    const int l = threadIdx.x;
    if (l >= NL) return;
    const int o = t & 1;
    const int Hp = o ? 32 : 31, Wp = o ? 31 : 32;
    float* wst = ws + (size_t)t * TSTRIDE;
    const int h = l / Wp, w = l - h * Wp;
    float na2 = 0.0f, nb2 = 0.0f;
#pragma unroll
    for (int dh = -1; dh <= 1; ++dh)
#pragma unroll
        for (int dw = -1; dw <= 1; ++dw) {
            const int hh = h + dh, ww = w + dw;
            if ((unsigned)hh < (unsigned)Hp && (unsigned)ww < (unsigned)Wp) {
                const int ll = hh * Wp + ww;
                na2 += wst[OFF_SA + ll];
                nb2 += wst[OFF_SB + ll];
            }
        }
    const float na = fmaxf(sqrtf(na2), 1e-4f);
    const float nb = fmaxf(sqrtf(nb2), 1e-4f);
    wst[OFF_INV + l] = 1.0f / (na * nb);
}

// ---------------- K3: S = Mh Mh^T (992x992, K=256) MFMA f16, f16 out ----------
__global__ __launch_bounds__(256) void k_gram(float* __restrict__ ws) {
    const int t = blockIdx.x & 7;
    const int u = blockIdx.x >> 3;    // 0..63
    const int i0 = (u >> 3) * 128, j0 = (u & 7) * 128;
    float* wst = ws + (size_t)t * TSTRIDE;
    const _Float16* __restrict__ M = (const _Float16*)(wst + OFF_MH);
    _Float16* __restrict__ S = (_Float16*)(wst + OFF_S);
    __shared__ __align__(16) _Float16 As[128 * 32];
    __shared__ __align__(16) _Float16 Bs[128 * 32];
    const int tid = threadIdx.x;
    const int wave = tid >> 6, lane = tid & 63;
    const int wm = wave & 1, wn = wave >> 1;
    const int l15 = lane & 15, quad = lane >> 4;
    floatx4 acc[4][4] = {};
    const int srow = tid >> 2;
    const int scol = (tid & 3) * 8;
    for (int k0 = 0; k0 < NC; k0 += 32) {
        __syncthreads();
        if (i0 + srow < NL)      gload16(&M[(i0 + srow) * NC + k0 + scol], &As[srow * 32 + scol]);
        if (i0 + 64 + srow < NL) gload16(&M[(i0 + 64 + srow) * NC + k0 + scol], &As[(64 + srow) * 32 + scol]);
        if (j0 + srow < NL)      gload16(&M[(j0 + srow) * NC + k0 + scol], &Bs[srow * 32 + scol]);
        if (j0 + 64 + srow < NL) gload16(&M[(j0 + 64 + srow) * NC + k0 + scol], &Bs[(64 + srow) * 32 + scol]);
        __syncthreads();
        half8 a[4], b[4];
#pragma unroll
        for (int mt = 0; mt < 4; ++mt) a[mt] = *(const half8*)&As[(wm * 64 + mt * 16 + l15) * 32 + quad * 8];
#pragma unroll
        for (int nt = 0; nt < 4; ++nt) b[nt] = *(const half8*)&Bs[(wn * 64 + nt * 16 + l15) * 32 + quad * 8];
#pragma unroll
        for (int mt = 0; mt < 4; ++mt)
#pragma unroll
            for (int nt = 0; nt < 4; ++nt)
                acc[mt][nt] = __builtin_amdgcn_mfma_f32_16x16x32_f16(a[mt], b[nt], acc[mt][nt], 0, 0, 0);
    }
#pragma unroll
    for (int mt = 0; mt < 4; ++mt)
#pragma unroll
        for (int nt = 0; nt < 4; ++nt)
#pragma unroll
            for (int r = 0; r < 4; ++r) {
                const int row = i0 + wm * 64 + mt * 16 + quad * 4 + r;
                const int col = j0 + wn * 64 + nt * 16 + l15;
                if (row < NL && col < NL) S[row * NL + col] = (_Float16)acc[mt][nt][r];
            }
}

// ---------------- K4: G = 9-pt band(S) -> softmax -> Ph (f16) ----------------
__global__ __launch_bounds__(256) void k_softmax(float* __restrict__ ws) {
    const int t = blockIdx.x & 7;
    const int l1 = blockIdx.x >> 3;
    const int o = t & 1;
    const int Hp = o ? 32 : 31, Wp = o ? 31 : 32;
    const unsigned MAGIC = o ? 33826u : 32768u;   // x/Wp = (x*MAGIC)>>20, x<1024
    float* wst = ws + (size_t)t * TSTRIDE;
    const _Float16* __restrict__ S = (const _Float16*)(wst + OFF_S);
    const float* __restrict__ inv = wst + OFF_INV;
    _Float16* __restrict__ Ph = (_Float16*)(wst + OFF_P);
    const int h1 = (int)((l1 * MAGIC) >> 20), w1 = l1 - h1 * Wp;
    bool ok1[3][3];
    const _Float16* rp[3][3];
#pragma unroll
    for (int ih = 0; ih < 3; ++ih)
#pragma unroll
        for (int iw = 0; iw < 3; ++iw) {
            const int dh = ih - 1, dw = iw - 1;
            ok1[ih][iw] = (unsigned)(h1 + dh) < (unsigned)Hp &&
                          (unsigned)(w1 + dw) < (unsigned)Wp;
            rp[ih][iw] = S + (l1 + dh * Wp + dw) * NL + dh * Wp + dw;
        }
    const float inv1 = inv[l1] * 10.0f;
    float lg[4];
    float mx = -3.0e38f;
#pragma unroll
    for (int j = 0; j < 4; ++j) {
        const int l2 = threadIdx.x + j * 256;
        if (l2 < NL) {
            const int h2 = (int)((l2 * MAGIC) >> 20), w2 = l2 - h2 * Wp;
            float G = 0.0f;
#pragma unroll
            for (int ih = 0; ih < 3; ++ih) {
                const int dh = ih - 1;
                const bool oh2 = (unsigned)(h2 + dh) < (unsigned)Hp;
#pragma unroll
                for (int iw = 0; iw < 3; ++iw) {
                    const int dw = iw - 1;
                    if (ok1[ih][iw] && oh2 && (unsigned)(w2 + dw) < (unsigned)Wp)
                        G += (float)rp[ih][iw][l2];
                }
            }
            lg[j] = G * inv1 * inv[l2];
            mx = fmaxf(mx, lg[j]);
        } else {
            lg[j] = -3.0e38f;
        }
    }
    __shared__ float red[4];
    const int wave = threadIdx.x >> 6, lane = threadIdx.x & 63;
#pragma unroll
    for (int off = 32; off > 0; off >>= 1) mx = fmaxf(mx, __shfl_down(mx, off));
    if (lane == 0) red[wave] = mx;
    __syncthreads();
    mx = fmaxf(fmaxf(red[0], red[1]), fmaxf(red[2], red[3]));
    __syncthreads();
    float e[4];
    float sum = 0.0f;
#pragma unroll
    for (int j = 0; j < 4; ++j) {
        const int l2 = threadIdx.x + j * 256;
        e[j] = __expf(lg[j] - mx);
        if (l2 < NL) sum += e[j];
    }
#pragma unroll
    for (int off = 32; off > 0; off >>= 1) sum += __shfl_down(sum, off);
    if (lane == 0) red[wave] = sum;
    __syncthreads();
    sum = red[0] + red[1] + red[2] + red[3];
    const float rs = 1.0f / sum;
#pragma unroll
    for (int j = 0; j < 4; ++j) {
        const int l2 = threadIdx.x + j * 256;
        if (l2 < NL) Ph[l1 * NL + l2] = (_Float16)(e[j] * rs);
    }
}

// ---------------- K5: Wh = 9-pt band(Ph) -> into S buffer ----------------
// W[m,c] = sum_e Ph[m+e, c+e], validity (hm+eh, wm+ew, hc+eh, wc+ew) in range
__global__ __launch_bounds__(256) void k_band9(float* __restrict__ ws) {
    const int t = blockIdx.x & 7;
    const int m = blockIdx.x >> 3;
    const int o = t & 1;
    const int Hp = o ? 32 : 31, Wp = o ? 31 : 32;
    const unsigned MAGIC = o ? 33826u : 32768u;
    float* wst = ws + (size_t)t * TSTRIDE;
    const _Float16* __restrict__ Ph = (const _Float16*)(wst + OFF_P);
    _Float16* __restrict__ Wh = (_Float16*)(wst + OFF_S);
    const int hm = (int)((m * MAGIC) >> 20), wm = m - hm * Wp;
    bool ok1[3][3];
    const _Float16* rp[3][3];
#pragma unroll
    for (int ih = 0; ih < 3; ++ih)
#pragma unroll
        for (int iw = 0; iw < 3; ++iw) {
            const int dh = ih - 1, dw = iw - 1;
            ok1[ih][iw] = (unsigned)(hm + dh) < (unsigned)Hp &&
                          (unsigned)(wm + dw) < (unsigned)Wp;
            rp[ih][iw] = Ph + (m + dh * Wp + dw) * NL + dh * Wp + dw;
        }
#pragma unroll
    for (int j = 0; j < 4; ++j) {
        const int c = threadIdx.x + j * 256;
        if (c < NL) {
            const int hc = (int)((c * MAGIC) >> 20), wc = c - hc * Wp;
            float acc = 0.0f;
#pragma unroll
            for (int ih = 0; ih < 3; ++ih) {
                const int dh = ih - 1;
                const bool oh = (unsigned)(hc + dh) < (unsigned)Hp;
#pragma unroll
                for (int iw = 0; iw < 3; ++iw) {
                    const int dw = iw - 1;
                    if (ok1[ih][iw] && oh && (unsigned)(wc + dw) < (unsigned)Wp)
                        acc += (float)rp[ih][iw][c];
                }
            }
            Wh[m * NL + c] = (_Float16)acc;
        }
    }
}

// ---------------- K6: Y = Wh @ ABt^T (992x512, K=992) MFMA f16 ----------------
__global__ __launch_bounds__(256) void k_recon(float* __restrict__ ws) {
    const int t = blockIdx.x & 7;
    const int u = blockIdx.x >> 3;    // 0..31 = 8 iy x 4 jx
    const int i0 = (u >> 2) * 128, j0 = (u & 3) * 128;
    float* wst = ws + (size_t)t * TSTRIDE;
    const _Float16* __restrict__ Wm = (const _Float16*)(wst + OFF_S);
    const _Float16* __restrict__ ABt = (const _Float16*)(wst + OFF_ABT);
    float* __restrict__ Y = wst + OFF_Y;
    __shared__ __align__(16) _Float16 As[128 * 32];
    __shared__ __align__(16) _Float16 Bs[128 * 32];
    const int tid = threadIdx.x;
    const int wave = tid >> 6, lane = tid & 63;
    const int wm = wave & 1, wn = wave >> 1;
    const int l15 = lane & 15, quad = lane >> 4;
    floatx4 acc[4][4] = {};
    const int srow = tid >> 2;
    const int scol = (tid & 3) * 8;
    for (int k0 = 0; k0 < NL; k0 += 32) {   // 31 exact iterations
        __syncthreads();
        if (i0 + srow < NL)      gload16(&Wm[(i0 + srow) * NL + k0 + scol], &As[srow * 32 + scol]);
        if (i0 + 64 + srow < NL) gload16(&Wm[(i0 + 64 + srow) * NL + k0 + scol], &As[(64 + srow) * 32 + scol]);
        gload16(&ABt[(j0 + srow) * NL + k0 + scol], &Bs[srow * 32 + scol]);
        gload16(&ABt[(j0 + 64 + srow) * NL + k0 + scol], &Bs[(64 + srow) * 32 + scol]);
        __syncthreads();
        half8 a[4], b[4];
#pragma unroll
        for (int mt = 0; mt < 4; ++mt) a[mt] = *(const half8*)&As[(wm * 64 + mt * 16 + l15) * 32 + quad * 8];
#pragma unroll
        for (int nt = 0; nt < 4; ++nt) b[nt] = *(const half8*)&Bs[(wn * 64 + nt * 16 + l15) * 32 + quad * 8];
#pragma unroll
        for (int mt = 0; mt < 4; ++mt)
#pragma unroll
            for (int nt = 0; nt < 4; ++nt)
                acc[mt][nt] = __builtin_amdgcn_mfma_f32_16x16x32_f16(a[mt], b[nt], acc[mt][nt], 0, 0, 0);
    }
#pragma unroll
    for (int mt = 0; mt < 4; ++mt)
#pragma unroll
        for (int nt = 0; nt < 4; ++nt)
#pragma unroll
            for (int r = 0; r < 4; ++r) {
                const int row = i0 + wm * 64 + mt * 16 + quad * 4 + r;
                const int col = j0 + wn * 64 + nt * 16 + l15;
                if (row < NL) Y[row * NC2 + col] = acc[mt][nt][r];
            }
}

// ---------------- K7: seam combine -> out ----------------
__global__ __launch_bounds__(256) void k_combine(float* __restrict__ out,
                                                 const float* __restrict__ ws) {
    const int idx = blockIdx.x;          // s*1024 + h*32 + w
    const int s = idx >> 10;
    const int hw = idx & 1023;
    const int h = hw >> 5, w = hw & 31;
    const int c = threadIdx.x;
    const float* Ylr = ws + (size_t)(2 * s) * TSTRIDE + OFF_Y;
    const float* Ytb = ws + (size_t)(2 * s + 1) * TSTRIDE + OFF_Y;
    float v = 0.0f;
    if (h < 31) v += Ylr[(h * 32 + w) * NC2 + NC + c] * (h == 0 ? 1.0f : 0.5f);
    if (h >= 1) v += Ylr[((h - 1) * 32 + w) * NC2 + c] * (h == 31 ? 1.0f : 0.5f);
    if (w < 31) v += Ytb[(h * 31 + w) * NC2 + c] * (w == 0 ? 1.0f : 0.5f);
    if (w >= 1) v += Ytb[(h * 31 + (w - 1)) * NC2 + NC + c] * (w == 31 ? 1.0f : 0.5f);
    out[(size_t)idx * NC + c] = v * 0.5f;
}

extern "C" void kernel_launch(void* const* d_in, const int* in_sizes, int n_in,
                              void* d_out, int out_size, void* d_ws, size_t ws_size,
                              hipStream_t stream) {
    const float* x = (const float*)d_in[0];
    float* out = (float*)d_out;
    float* ws = (float*)d_ws;    // 8*TSTRIDE*4 = 60 MB

    hipLaunchKernelGGL(k_prep,    dim3(8 * NL),  dim3(256),  0, stream, x, ws);
    hipLaunchKernelGGL(k_abt,     dim3(8 * 496), dim3(256),  0, stream, x, ws);
    hipLaunchKernelGGL(k_inv,     dim3(8),       dim3(1024), 0, stream, ws);
    hipLaunchKernelGGL(k_gram,    dim3(8 * 64),  dim3(256),  0, stream, ws);
    hipLaunchKernelGGL(k_softmax, dim3(8 * NL),  dim3(256),  0, stream, ws);
    hipLaunchKernelGGL(k_band9,   dim3(8 * NL),  dim3(256),  0, stream, ws);
    hipLaunchKernelGGL(k_recon,   dim3(8 * 32),  dim3(256),  0, stream, ws);
    hipLaunchKernelGGL(k_combine, dim3(4096),    dim3(256),  0, stream, out, ws);
}

// Round 5
// 154.842 us; speedup vs baseline: 1.2764x; 1.2764x over previous
//
#include <hip/hip_runtime.h>

// B=4, H=W=32, C=256. 8 tasks (sample x orientation), grid L=992 each.
// Pipeline: Mh=f16(a*b) -> S = Mh Mh^T (MFMA, f16 -> B0)
//   Sw = w-band(S)  [k_bandw, B0->B1]        (3-pt diagonal, vector loads)
//   G = h-band(Sw) fused in softmax -> Ph    [B1->B0]
//   Wh = 9-pt band(Ph)                        [k_band9p, B0->B1]
//   Y = Wh @ ABt^T (MFMA f16, f32 out) -> seam combine.
// Stencil kernels use unconditional 4B-aligned vector loads + mask-as-select
// (predicated scalar loads were the R4 bottleneck). Wp/Hp are template params
// so diagonal-shift parities (extraction indices) are compile-time.

typedef _Float16 half8 __attribute__((ext_vector_type(8)));
typedef _Float16 half8u __attribute__((ext_vector_type(8), aligned(4)));
typedef _Float16 half4h __attribute__((ext_vector_type(4)));
typedef _Float16 half4u __attribute__((ext_vector_type(4), aligned(8)));
typedef float floatx4 __attribute__((ext_vector_type(4)));

constexpr int NL = 992, NC = 256, NC2 = 512;
constexpr int NLL = NL * NL;
// float-granular per-task offsets. B0/B1 placed LAST so their +-65KB
// stencil over/under-reads stay inside d_ws (leading slack = ABT/MH/Y).
constexpr int OFF_ABT = 0;                      // f16 [512][992]
constexpr int OFF_MH  = OFF_ABT + NL * NC2 / 2; // f16 [992][256]
constexpr int OFF_SA  = OFF_MH + NL * NC / 2;
constexpr int OFF_SB  = OFF_SA + 1024;
constexpr int OFF_INV = OFF_SA + 2048;
constexpr int OFF_Y   = OFF_SA + 3072;          // f32 [992][512]
constexpr int OFF_B0  = OFF_Y + NL * NC2;       // f16 LxL: S, later Ph
constexpr int OFF_B1  = OFF_B0 + NLL / 2;       // f16 LxL: Sw, later Wh
constexpr int TSTRIDE = OFF_B1 + NLL / 2;       // 1,875,968 f -> 60 MB total

__device__ __forceinline__ void gload16(const void* g, void* l) {
    __builtin_amdgcn_global_load_lds(
        (const __attribute__((address_space(1))) unsigned int*)g,
        (__attribute__((address_space(3))) unsigned int*)(unsigned long)(uintptr_t)l,
        16, 0, 0);
}

// ---------------- K1: Mh = f16(a*b), per-pixel squared norms ----------------
__global__ __launch_bounds__(256) void k_prep(const float* __restrict__ x,
                                              float* __restrict__ ws) {
    const int t = blockIdx.x & 7;
    const int l = blockIdx.x >> 3;
    const int s = t >> 1, o = t & 1;
    int aoff, boff;
    if (o == 0) {  // lr grid (31,32)
        const int lh = l >> 5, lw = l & 31;
        aoff = ((s * 32 + lh) * 32 + lw) * NC;
        boff = ((s * 32 + lh + 1) * 32 + lw) * NC;
    } else {       // tb grid (32,31)
        const int lh = l / 31, lw = l - lh * 31;
        aoff = ((s * 32 + lh) * 32 + lw + 1) * NC;
        boff = ((s * 32 + lh) * 32 + lw) * NC;
    }
    float* wst = ws + (size_t)t * TSTRIDE;
    const int c = threadIdx.x;
    const float av = x[aoff + c];
    const float bv = x[boff + c];
    ((_Float16*)(wst + OFF_MH))[l * NC + c] = (_Float16)(av * bv);
    float ra = av * av, rb = bv * bv;
#pragma unroll
    for (int off = 32; off > 0; off >>= 1) {
        ra += __shfl_down(ra, off);
        rb += __shfl_down(rb, off);
    }
    __shared__ float shA[4], shB[4];
    const int wave = threadIdx.x >> 6, lane = threadIdx.x & 63;
    if (lane == 0) { shA[wave] = ra; shB[wave] = rb; }
    __syncthreads();
    if (threadIdx.x == 0) {
        wst[OFF_SA + l] = shA[0] + shA[1] + shA[2] + shA[3];
        wst[OFF_SB + l] = shB[0] + shB[1] + shB[2] + shB[3];
    }
}

// ---------------- K1b: ABt[c][l] (f16) via 32x32 LDS transpose ----------------
__global__ __launch_bounds__(256) void k_abt(const float* __restrict__ x,
                                             float* __restrict__ ws) {
    const int t = blockIdx.x & 7;
    const int u = blockIdx.x >> 3;    // 0..495 = 16 cblk x 31 lblk
    const int cbk = u / 31;
    const int c0 = cbk * 32;
    const int l0 = (u - cbk * 31) * 32;
    const int s = t >> 1, o = t & 1;
    float* wst = ws + (size_t)t * TSTRIDE;
    _Float16* __restrict__ ABt = (_Float16*)(wst + OFF_ABT);
    __shared__ float T[32 * 33];
    const int tid = threadIdx.x;
    const bool isB = (c0 >= 256);
    const int cb = isB ? c0 - 256 : c0;
    {
        const int li = tid >> 3, cq = tid & 7;
        const int l = l0 + li;
        int xoff;
        if (o == 0) {
            const int lh = l >> 5, lw = l & 31;
            xoff = isB ? ((s * 32 + lh + 1) * 32 + lw) : ((s * 32 + lh) * 32 + lw);
        } else {
            const int lh = l / 31, lw = l - lh * 31;
            xoff = isB ? ((s * 32 + lh) * 32 + lw) : ((s * 32 + lh) * 32 + lw + 1);
        }
        const float4 v = *(const float4*)&x[xoff * NC + cb + cq * 4];
        T[(cq * 4 + 0) * 33 + li] = v.x;
        T[(cq * 4 + 1) * 33 + li] = v.y;
        T[(cq * 4 + 2) * 33 + li] = v.z;
        T[(cq * 4 + 3) * 33 + li] = v.w;
    }
    __syncthreads();
    {
        const int ci = tid >> 3, lq = tid & 7;
        half4h h;
        h.x = (_Float16)T[ci * 33 + lq * 4 + 0];
        h.y = (_Float16)T[ci * 33 + lq * 4 + 1];
        h.z = (_Float16)T[ci * 33 + lq * 4 + 2];
        h.w = (_Float16)T[ci * 33 + lq * 4 + 3];
        *(half4h*)&ABt[(c0 + ci) * NL + l0 + lq * 4] = h;
    }
}

// ---------------- K2: inv from 3x3 box sums of squared norms ----------------
__global__ __launch_bounds__(1024) void k_inv(float* __restrict__ ws) {
    const int t = blockIdx.x;
    const int l = threadIdx.x;
    if (l >= NL) return;
    const int o = t & 1;
    const int Hp = o ? 32 : 31, Wp = o ? 31 : 32;
    float* wst = ws + (size_t)t * TSTRIDE;
    const int h = l / Wp, w = l - h * Wp;
    float na2 = 0.0f, nb2 = 0.0f;
#pragma unroll
    for (int dh = -1; dh <= 1; ++dh)
#pragma unroll
        for (int dw = -1; dw <= 1; ++dw) {
            const int hh = h + dh, ww = w + dw;
            if ((unsigned)hh < (unsigned)Hp && (unsigned)ww < (unsigned)Wp) {
                const int ll = hh * Wp + ww;
                na2 += wst[OFF_SA + ll];
                nb2 += wst[OFF_SB + ll];
            }
        }
    const float na = fmaxf(sqrtf(na2), 1e-4f);
    const float nb = fmaxf(sqrtf(nb2), 1e-4f);
    wst[OFF_INV + l] = 1.0f / (na * nb);
}

// ---------------- K3: S = Mh Mh^T (992x992, K=256) MFMA f16 -> B0 ----------
__global__ __launch_bounds__(256) void k_gram(float* __restrict__ ws) {
    const int t = blockIdx.x & 7;
    const int u = blockIdx.x >> 3;    // 0..63
    const int i0 = (u >> 3) * 128, j0 = (u & 7) * 128;
    float* wst = ws + (size_t)t * TSTRIDE;
    const _Float16* __restrict__ M = (const _Float16*)(wst + OFF_MH);
    _Float16* __restrict__ S = (_Float16*)(wst + OFF_B0);
    __shared__ __align__(16) _Float16 As[128 * 32];
    __shared__ __align__(16) _Float16 Bs[128 * 32];
    const int tid = threadIdx.x;
    const int wave = tid >> 6, lane = tid & 63;
    const int wm = wave & 1, wn = wave >> 1;
    const int l15 = lane & 15, quad = lane >> 4;
    floatx4 acc[4][4] = {};
    const int srow = tid >> 2;
    const int scol = (tid & 3) * 8;
    for (int k0 = 0; k0 < NC; k0 += 32) {
        __syncthreads();
        if (i0 + srow < NL)      gload16(&M[(i0 + srow) * NC + k0 + scol], &As[srow * 32 + scol]);
        if (i0 + 64 + srow < NL) gload16(&M[(i0 + 64 + srow) * NC + k0 + scol], &As[(64 + srow) * 32 + scol]);
        if (j0 + srow < NL)      gload16(&M[(j0 + srow) * NC + k0 + scol], &Bs[srow * 32 + scol]);
        if (j0 + 64 + srow < NL) gload16(&M[(j0 + 64 + srow) * NC + k0 + scol], &Bs[(64 + srow) * 32 + scol]);
        __syncthreads();
        half8 a[4], b[4];
#pragma unroll
        for (int mt = 0; mt < 4; ++mt) a[mt] = *(const half8*)&As[(wm * 64 + mt * 16 + l15) * 32 + quad * 8];
#pragma unroll
        for (int nt = 0; nt < 4; ++nt) b[nt] = *(const half8*)&Bs[(wn * 64 + nt * 16 + l15) * 32 + quad * 8];
#pragma unroll
        for (int mt = 0; mt < 4; ++mt)
#pragma unroll
            for (int nt = 0; nt < 4; ++nt)
                acc[mt][nt] = __builtin_amdgcn_mfma_f32_16x16x32_f16(a[mt], b[nt], acc[mt][nt], 0, 0, 0);
    }
#pragma unroll
    for (int mt = 0; mt < 4; ++mt)
#pragma unroll
        for (int nt = 0; nt < 4; ++nt)
#pragma unroll
            for (int r = 0; r < 4; ++r) {
                const int row = i0 + wm * 64 + mt * 16 + quad * 4 + r;
                const int col = j0 + wn * 64 + nt * 16 + l15;
                if (row < NL && col < NL) S[row * NL + col] = (_Float16)acc[mt][nt][r];
            }
}

// ---------------- K4: w-band pass, B0 -> B1 ----------------
// D[r,c] = S[r,c] + [wr>0 & wc>0] S[r-1,c-1] + [wr+1<WP & wc+1<WP] S[r+1,c+1]
template<int WP>
__device__ __forceinline__ void bandw_body(const _Float16* __restrict__ S,
                                           _Float16* __restrict__ D,
                                           const int r, const int tid) {
    if (tid >= 248) return;
    const int c0 = tid * 4;
    const int w1 = r % WP;
    const bool okm = (w1 > 0), okp = (w1 + 1 < WP);
    float acc[4];
    const half4u v0 = *(const half4u*)(S + r * NL + c0);
#pragma unroll
    for (int j = 0; j < 4; ++j) acc[j] = (float)v0[j];
    if (okm) {  // row r-1, cols c0-1..c0+2 -> elems 1..4 of half8 @ c0-2
        const half8u vm = *(const half8u*)(S + (r - 1) * NL + c0 - 2);
#pragma unroll
        for (int j = 0; j < 4; ++j)
            if ((c0 + j) % WP > 0) acc[j] += (float)vm[j + 1];
    }
    if (okp) {  // row r+1, cols c0+1..c0+4 -> elems 1..4 of half8 @ c0
        const half8u vp = *(const half8u*)(S + (r + 1) * NL + c0);
#pragma unroll
        for (int j = 0; j < 4; ++j)
            if ((c0 + j) % WP + 1 < WP) acc[j] += (float)vp[j + 1];
    }
    half4h o;
#pragma unroll
    for (int j = 0; j < 4; ++j) o[j] = (_Float16)acc[j];
    *(half4u*)(D + r * NL + c0) = o;
}

__global__ __launch_bounds__(256) void k_bandw(float* __restrict__ ws) {
    const int t = blockIdx.x & 7;
    const int r = blockIdx.x >> 3;
    float* wst = ws + (size_t)t * TSTRIDE;
    const _Float16* S = (const _Float16*)(wst + OFF_B0);
    _Float16* D = (_Float16*)(wst + OFF_B1);
    if (t & 1) bandw_body<31>(S, D, r, threadIdx.x);
    else       bandw_body<32>(S, D, r, threadIdx.x);
}

// ---------------- K5: h-band(Sw) -> softmax -> Ph, B1 -> B0 ----------------
template<int WP, int HP>
__device__ __forceinline__ void softmax_body(float* __restrict__ wst,
                                             const int l1, const int tid) {
    const _Float16* __restrict__ Sw = (const _Float16*)(wst + OFF_B1);
    const float* __restrict__ inv = wst + OFF_INV;
    _Float16* __restrict__ Ph = (_Float16*)(wst + OFF_B0);
    constexpr int SH = WP * (NL + 1);
    constexpr int PAR = SH & 1;
    const int h1 = l1 / WP;
    const bool okm = (h1 > 0), okp = (h1 + 1 < HP);
    const float inv1 = inv[l1] * 10.0f;
    const int c0 = tid * 4;
    float lg[4] = {-3.0e38f, -3.0e38f, -3.0e38f, -3.0e38f};
    float mx = -3.0e38f;
    if (tid < 248) {
        float g[4];
        const half4u v0 = *(const half4u*)(Sw + l1 * NL + c0);
#pragma unroll
        for (int j = 0; j < 4; ++j) g[j] = (float)v0[j];
        if (okm) {  // row l1-WP, cols c-WP -> elems j+PAR of half8 @ c0-SH-PAR
            const half8u vm = *(const half8u*)(Sw + l1 * NL + c0 - SH - PAR);
#pragma unroll
            for (int j = 0; j < 4; ++j)
                if (c0 + j >= WP) g[j] += (float)vm[j + PAR];
        }
        if (okp) {  // row l1+WP, cols c+WP -> elems j+PAR of half8 @ c0+SH-PAR
            const half8u vp = *(const half8u*)(Sw + l1 * NL + c0 + SH - PAR);
#pragma unroll
            for (int j = 0; j < 4; ++j)
                if (c0 + j < NL - WP) g[j] += (float)vp[j + PAR];
        }
#pragma unroll
        for (int j = 0; j < 4; ++j) {
            lg[j] = g[j] * inv1 * inv[c0 + j];
            mx = fmaxf(mx, lg[j]);
        }
    }
    __shared__ float red[4];
    const int wave = tid >> 6, lane = tid & 63;
#pragma unroll
    for (int off = 32; off > 0; off >>= 1) mx = fmaxf(mx, __shfl_down(mx, off));
    if (lane == 0) red[wave] = mx;
    __syncthreads();
    mx = fmaxf(fmaxf(red[0], red[1]), fmaxf(red[2], red[3]));
    __syncthreads();
    float e[4];
    float sum = 0.0f;
#pragma unroll
    for (int j = 0; j < 4; ++j) { e[j] = __expf(lg[j] - mx); sum += e[j]; }
    if (tid >= 248) sum = 0.0f;
#pragma unroll
    for (int off = 32; off > 0; off >>= 1) sum += __shfl_down(sum, off);
    if (lane == 0) red[wave] = sum;
    __syncthreads();
    sum = red[0] + red[1] + red[2] + red[3];
    const float rs = 1.0f / sum;
    if (tid < 248) {
        half4h o;
#pragma unroll
        for (int j = 0; j < 4; ++j) o[j] = (_Float16)(e[j] * rs);
        *(half4u*)(Ph + l1 * NL + c0) = o;
    }
}

__global__ __launch_bounds__(256) void k_softmax(float* __restrict__ ws) {
    const int t = blockIdx.x & 7;
    const int l1 = blockIdx.x >> 3;
    float* wst = ws + (size_t)t * TSTRIDE;
    if (t & 1) softmax_body<31, 32>(wst, l1, threadIdx.x);
    else       softmax_body<32, 31>(wst, l1, threadIdx.x);
}

// ---------------- K6: Wh = 9-pt band(Ph), B0 -> B1 ----------------
template<int WP, int HP>
__device__ __forceinline__ void band9p_body(float* __restrict__ wst,
                                            const int m, const int tid) {
    if (tid >= 248) return;
    const _Float16* __restrict__ P = (const _Float16*)(wst + OFF_B0);
    _Float16* __restrict__ W = (_Float16*)(wst + OFF_B1);
    const int c0 = tid * 4;
    const int hm = m / WP, wm = m % WP;
    int hc[4], wc[4];
#pragma unroll
    for (int j = 0; j < 4; ++j) { hc[j] = (c0 + j) / WP; wc[j] = (c0 + j) % WP; }
    float acc[4] = {0.f, 0.f, 0.f, 0.f};
    const _Float16* base = P + m * NL + c0;
#pragma unroll
    for (int dh = -1; dh <= 1; ++dh) {
        const bool oh1 = (unsigned)(hm + dh) < (unsigned)HP;
#pragma unroll
        for (int dw = -1; dw <= 1; ++dw) {
            const int sh = dh * WP + dw;        // compile-time after unroll
            const int par = sh & 1;
            const bool ok1 = oh1 && (unsigned)(wm + dw) < (unsigned)WP;
            const half8u v = *(const half8u*)(base + sh * (NL + 1) - par);
#pragma unroll
            for (int j = 0; j < 4; ++j) {
                const bool ok = ok1 && (unsigned)(hc[j] + dh) < (unsigned)HP &&
                                       (unsigned)(wc[j] + dw) < (unsigned)WP;
                if (ok) acc[j] += (float)v[j + par];
            }
        }
    }
    half4h o;
#pragma unroll
    for (int j = 0; j < 4; ++j) o[j] = (_Float16)acc[j];
    *(half4u*)(W + m * NL + c0) = o;
}

__global__ __launch_bounds__(256) void k_band9p(float* __restrict__ ws) {
    const int t = blockIdx.x & 7;
    const int m = blockIdx.x >> 3;
    float* wst = ws + (size_t)t * TSTRIDE;
    if (t & 1) band9p_body<31, 32>(wst, m, threadIdx.x);
    else       band9p_body<32, 31>(wst, m, threadIdx.x);
}

// ---------------- K7: Y = Wh @ ABt^T (992x512, K=992) MFMA f16 ----------------
__global__ __launch_bounds__(256) void k_recon(float* __restrict__ ws) {
    const int t = blockIdx.x & 7;
    const int u = blockIdx.x >> 3;    // 0..31 = 8 iy x 4 jx
    const int i0 = (u >> 2) * 128, j0 = (u & 3) * 128;
    float* wst = ws + (size_t)t * TSTRIDE;
    const _Float16* __restrict__ Wm = (const _Float16*)(wst + OFF_B1);
    const _Float16* __restrict__ ABt = (const _Float16*)(wst + OFF_ABT);
    float* __restrict__ Y = wst + OFF_Y;
    __shared__ __align__(16) _Float16 As[128 * 32];
    __shared__ __align__(16) _Float16 Bs[128 * 32];
    const int tid = threadIdx.x;
    const int wave = tid >> 6, lane = tid & 63;
    const int wm = wave & 1, wn = wave >> 1;
    const int l15 = lane & 15, quad = lane >> 4;
    floatx4 acc[4][4] = {};
    const int srow = tid >> 2;
    const int scol = (tid & 3) * 8;
    for (int k0 = 0; k0 < NL; k0 += 32) {   // 31 exact iterations
        __syncthreads();
        if (i0 + srow < NL)      gload16(&Wm[(i0 + srow) * NL + k0 + scol], &As[srow * 32 + scol]);
        if (i0 + 64 + srow < NL) gload16(&Wm[(i0 + 64 + srow) * NL + k0 + scol], &As[(64 + srow) * 32 + scol]);
        gload16(&ABt[(j0 + srow) * NL + k0 + scol], &Bs[srow * 32 + scol]);
        gload16(&ABt[(j0 + 64 + srow) * NL + k0 + scol], &Bs[(64 + srow) * 32 + scol]);
        __syncthreads();
        half8 a[4], b[4];
#pragma unroll
        for (int mt = 0; mt < 4; ++mt) a[mt] = *(const half8*)&As[(wm * 64 + mt * 16 + l15) * 32 + quad * 8];
#pragma unroll
        for (int nt = 0; nt < 4; ++nt) b[nt] = *(const half8*)&Bs[(wn * 64 + nt * 16 + l15) * 32 + quad * 8];
#pragma unroll
        for (int mt = 0; mt < 4; ++mt)
#pragma unroll
            for (int nt = 0; nt < 4; ++nt)
                acc[mt][nt] = __builtin_amdgcn_mfma_f32_16x16x32_f16(a[mt], b[nt], acc[mt][nt], 0, 0, 0);
    }
#pragma unroll
    for (int mt = 0; mt < 4; ++mt)
#pragma unroll
        for (int nt = 0; nt < 4; ++nt)
#pragma unroll
            for (int r = 0; r < 4; ++r) {
                const int row = i0 + wm * 64 + mt * 16 + quad * 4 + r;
                const int col = j0 + wn * 64 + nt * 16 + l15;
                if (row < NL) Y[row * NC2 + col] = acc[mt][nt][r];
            }
}

// ---------------- K8: seam combine -> out ----------------
__global__ __launch_bounds__(256) void k_combine(float* __restrict__ out,
                                                 const float* __restrict__ ws) {
    const int idx = blockIdx.x;          // s*1024 + h*32 + w
    const int s = idx >> 10;
    const int hw = idx & 1023;
    const int h = hw >> 5, w = hw & 31;
    const int c = threadIdx.x;
    const float* Ylr = ws + (size_t)(2 * s) * TSTRIDE + OFF_Y;
    const float* Ytb = ws + (size_t)(2 * s + 1) * TSTRIDE + OFF_Y;
    float v = 0.0f;
    if (h < 31) v += Ylr[(h * 32 + w) * NC2 + NC + c] * (h == 0 ? 1.0f : 0.5f);
    if (h >= 1) v += Ylr[((h - 1) * 32 + w) * NC2 + c] * (h == 31 ? 1.0f : 0.5f);
    if (w < 31) v += Ytb[(h * 31 + w) * NC2 + c] * (w == 0 ? 1.0f : 0.5f);
    if (w >= 1) v += Ytb[(h * 31 + (w - 1)) * NC2 + NC + c] * (w == 31 ? 1.0f : 0.5f);
    out[(size_t)idx * NC + c] = v * 0.5f;
}

extern "C" void kernel_launch(void* const* d_in, const int* in_sizes, int n_in,
                              void* d_out, int out_size, void* d_ws, size_t ws_size,
                              hipStream_t stream) {
    const float* x = (const float*)d_in[0];
    float* out = (float*)d_out;
    float* ws = (float*)d_ws;    // 8*TSTRIDE*4 = 60 MB

    hipLaunchKernelGGL(k_prep,    dim3(8 * NL),  dim3(256),  0, stream, x, ws);
    hipLaunchKernelGGL(k_abt,     dim3(8 * 496), dim3(256),  0, stream, x, ws);
    hipLaunchKernelGGL(k_inv,     dim3(8),       dim3(1024), 0, stream, ws);
    hipLaunchKernelGGL(k_gram,    dim3(8 * 64),  dim3(256),  0, stream, ws);
    hipLaunchKernelGGL(k_bandw,   dim3(8 * NL),  dim3(256),  0, stream, ws);
    hipLaunchKernelGGL(k_softmax, dim3(8 * NL),  dim3(256),  0, stream, ws);
    hipLaunchKernelGGL(k_band9p,  dim3(8 * NL),  dim3(256),  0, stream, ws);
    hipLaunchKernelGGL(k_recon,   dim3(8 * 32),  dim3(256),  0, stream, ws);
    hipLaunchKernelGGL(k_combine, dim3(4096),    dim3(256),  0, stream, out, ws);
}

// Round 6
// 149.377 us; speedup vs baseline: 1.3231x; 1.0366x over previous
//
#include <hip/hip_runtime.h>

// B=4, H=W=32, C=256. 8 tasks (sample x orientation), grid L=992 each.
// Pipeline (7 dispatches):
//   k_stage: Mh=f16(a*b), ABt (transposed f16 a|b), per-pixel sq norms
//   k_inv:   3x3 box sums -> inv
//   k_gram:  S = Mh Mh^T (MFMA f16 -> B0)
//   k_softmax9: G = 9-pt band(S) fused -> softmax -> Ph (B0->B1)
//   k_band9p:   Wh = 9-pt band(Ph)              (B1->B0)
//   k_recon: Y = Wh @ ABt^T (MFMA f16, f32 out)
//   k_combine: seam average -> out
// Stencils: unconditional 4B-aligned vector loads + mask-as-select (R5 win);
// WP/HP template params make diagonal-shift parities compile-time.

typedef _Float16 half8 __attribute__((ext_vector_type(8)));
typedef _Float16 half8u __attribute__((ext_vector_type(8), aligned(4)));
typedef _Float16 half4h __attribute__((ext_vector_type(4)));
typedef _Float16 half4u __attribute__((ext_vector_type(4), aligned(8)));
typedef float floatx4 __attribute__((ext_vector_type(4)));

constexpr int NL = 992, NC = 256, NC2 = 512;
constexpr int NLL = NL * NL;
// float-granular per-task offsets. B0/B1 last: their +-65KB stencil
// over/under-reads stay inside d_ws (ws is 256MB, we use 60MB).
constexpr int OFF_ABT = 0;                      // f16 [512][992]
constexpr int OFF_MH  = OFF_ABT + NL * NC2 / 2; // f16 [992][256]
constexpr int OFF_SA  = OFF_MH + NL * NC / 2;
constexpr int OFF_SB  = OFF_SA + 1024;
constexpr int OFF_INV = OFF_SA + 2048;
constexpr int OFF_Y   = OFF_SA + 3072;          // f32 [992][512]
constexpr int OFF_B0  = OFF_Y + NL * NC2;       // f16 LxL: S, later Wh
constexpr int OFF_B1  = OFF_B0 + NLL / 2;       // f16 LxL: Ph
constexpr int TSTRIDE = OFF_B1 + NLL / 2;       // 1,875,968 f -> 60 MB total

__device__ __forceinline__ void gload16(const void* g, void* l) {
    __builtin_amdgcn_global_load_lds(
        (const __attribute__((address_space(1))) unsigned int*)g,
        (__attribute__((address_space(3))) unsigned int*)(unsigned long)(uintptr_t)l,
        16, 0, 0);
}

// ------- K1: one x-pass -> Mh, ABt (both halves), per-pixel sq norms -------
__global__ __launch_bounds__(256) void k_stage(const float* __restrict__ x,
                                               float* __restrict__ ws) {
    const int t = blockIdx.x & 7;
    const int l0 = (blockIdx.x >> 3) * 32;   // 31 l-blocks
    const int s = t >> 1, o = t & 1;
    float* wst = ws + (size_t)t * TSTRIDE;
    _Float16* __restrict__ ABt = (_Float16*)(wst + OFF_ABT);
    _Float16* __restrict__ Mh = (_Float16*)(wst + OFF_MH);
    __shared__ float Ta[32 * 33], Tb[32 * 33];
    const int tid = threadIdx.x;
    const int li = tid >> 3, cq = tid & 7;
    const int l = l0 + li;
    int aoff, boff;
    if (o == 0) {  // lr grid (31,32): a=x[s,lh,lw], b=x[s,lh+1,lw]
        const int lh = l >> 5, lw = l & 31;
        aoff = ((s * 32 + lh) * 32 + lw) * NC;
        boff = aoff + 32 * NC;
    } else {       // tb grid (32,31): a=x[s,lh,lw+1], b=x[s,lh,lw]
        const int lh = l / 31, lw = l - lh * 31;
        boff = ((s * 32 + lh) * 32 + lw) * NC;
        aoff = boff + NC;
    }
    float sa = 0.0f, sb = 0.0f;
    for (int cc = 0; cc < 8; ++cc) {
        const int c0 = cc * 32;
        const float4 a4 = *(const float4*)&x[aoff + c0 + cq * 4];
        const float4 b4 = *(const float4*)&x[boff + c0 + cq * 4];
        half4h m;
        m[0] = (_Float16)(a4.x * b4.x); m[1] = (_Float16)(a4.y * b4.y);
        m[2] = (_Float16)(a4.z * b4.z); m[3] = (_Float16)(a4.w * b4.w);
        *(half4u*)&Mh[l * NC + c0 + cq * 4] = m;
        sa += a4.x * a4.x + a4.y * a4.y + a4.z * a4.z + a4.w * a4.w;
        sb += b4.x * b4.x + b4.y * b4.y + b4.z * b4.z + b4.w * b4.w;
        __syncthreads();   // guard previous iteration's LDS reads
        Ta[(cq * 4 + 0) * 33 + li] = a4.x; Tb[(cq * 4 + 0) * 33 + li] = b4.x;
        Ta[(cq * 4 + 1) * 33 + li] = a4.y; Tb[(cq * 4 + 1) * 33 + li] = b4.y;
        Ta[(cq * 4 + 2) * 33 + li] = a4.z; Tb[(cq * 4 + 2) * 33 + li] = b4.z;
        Ta[(cq * 4 + 3) * 33 + li] = a4.w; Tb[(cq * 4 + 3) * 33 + li] = b4.w;
        __syncthreads();
        // transposed writes: thread (ci, lq) -> ABt[c0+ci][l0 + lq*4 ..]
        const int ci = li, lq = cq;
        half4h ha, hb;
#pragma unroll
        for (int j = 0; j < 4; ++j) {
            ha[j] = (_Float16)Ta[ci * 33 + lq * 4 + j];
            hb[j] = (_Float16)Tb[ci * 33 + lq * 4 + j];
        }
        *(half4u*)&ABt[(c0 + ci) * NL + l0 + lq * 4] = ha;
        *(half4u*)&ABt[(NC + c0 + ci) * NL + l0 + lq * 4] = hb;
    }
    // row sums: reduce the 8 cq-lanes (contiguous within a wave)
#pragma unroll
    for (int off = 4; off > 0; off >>= 1) {
        sa += __shfl_down(sa, off, 8);
        sb += __shfl_down(sb, off, 8);
    }
    if (cq == 0) {
        wst[OFF_SA + l] = sa;
        wst[OFF_SB + l] = sb;
    }
}

// ---------------- K2: inv from 3x3 box sums of squared norms ----------------
__global__ __launch_bounds__(1024) void k_inv(float* __restrict__ ws) {
    const int t = blockIdx.x;
    const int l = threadIdx.x;
    if (l >= NL) return;
    const int o = t & 1;
    const int Hp = o ? 32 : 31, Wp = o ? 31 : 32;
    float* wst = ws + (size_t)t * TSTRIDE;
    const int h = l / Wp, w = l - h * Wp;
    float na2 = 0.0f, nb2 = 0.0f;
#pragma unroll
    for (int dh = -1; dh <= 1; ++dh)
#pragma unroll
        for (int dw = -1; dw <= 1; ++dw) {
            const int hh = h + dh, ww = w + dw;
            if ((unsigned)hh < (unsigned)Hp && (unsigned)ww < (unsigned)Wp) {
                const int ll = hh * Wp + ww;
                na2 += wst[OFF_SA + ll];
                nb2 += wst[OFF_SB + ll];
            }
        }
    const float na = fmaxf(sqrtf(na2), 1e-4f);
    const float nb = fmaxf(sqrtf(nb2), 1e-4f);
    wst[OFF_INV + l] = 1.0f / (na * nb);
}

// ---------------- K3: S = Mh Mh^T (992x992, K=256) MFMA f16 -> B0 ----------
__global__ __launch_bounds__(256) void k_gram(float* __restrict__ ws) {
    const int t = blockIdx.x & 7;
    const int u = blockIdx.x >> 3;    // 0..63
    const int i0 = (u >> 3) * 128, j0 = (u & 7) * 128;
    float* wst = ws + (size_t)t * TSTRIDE;
    const _Float16* __restrict__ M = (const _Float16*)(wst + OFF_MH);
    _Float16* __restrict__ S = (_Float16*)(wst + OFF_B0);
    __shared__ __align__(16) _Float16 As[128 * 32];
    __shared__ __align__(16) _Float16 Bs[128 * 32];
    const int tid = threadIdx.x;
    const int wave = tid >> 6, lane = tid & 63;
    const int wm = wave & 1, wn = wave >> 1;
    const int l15 = lane & 15, quad = lane >> 4;
    floatx4 acc[4][4] = {};
    const int srow = tid >> 2;
    const int scol = (tid & 3) * 8;
    for (int k0 = 0; k0 < NC; k0 += 32) {
        __syncthreads();
        if (i0 + srow < NL)      gload16(&M[(i0 + srow) * NC + k0 + scol], &As[srow * 32 + scol]);
        if (i0 + 64 + srow < NL) gload16(&M[(i0 + 64 + srow) * NC + k0 + scol], &As[(64 + srow) * 32 + scol]);
        if (j0 + srow < NL)      gload16(&M[(j0 + srow) * NC + k0 + scol], &Bs[srow * 32 + scol]);
        if (j0 + 64 + srow < NL) gload16(&M[(j0 + 64 + srow) * NC + k0 + scol], &Bs[(64 + srow) * 32 + scol]);
        __syncthreads();
        half8 a[4], b[4];
#pragma unroll
        for (int mt = 0; mt < 4; ++mt) a[mt] = *(const half8*)&As[(wm * 64 + mt * 16 + l15) * 32 + quad * 8];
#pragma unroll
        for (int nt = 0; nt < 4; ++nt) b[nt] = *(const half8*)&Bs[(wn * 64 + nt * 16 + l15) * 32 + quad * 8];
#pragma unroll
        for (int mt = 0; mt < 4; ++mt)
#pragma unroll
            for (int nt = 0; nt < 4; ++nt)
                acc[mt][nt] = __builtin_amdgcn_mfma_f32_16x16x32_f16(a[mt], b[nt], acc[mt][nt], 0, 0, 0);
    }
#pragma unroll
    for (int mt = 0; mt < 4; ++mt)
#pragma unroll
        for (int nt = 0; nt < 4; ++nt)
#pragma unroll
            for (int r = 0; r < 4; ++r) {
                const int row = i0 + wm * 64 + mt * 16 + quad * 4 + r;
                const int col = j0 + wn * 64 + nt * 16 + l15;
                if (row < NL && col < NL) S[row * NL + col] = (_Float16)acc[mt][nt][r];
            }
}

// -------- K4: G = 9-pt band(S) fused -> softmax -> Ph, B0 -> B1 --------
template<int WP, int HP>
__device__ __forceinline__ void softmax9_body(float* __restrict__ wst,
                                              const int l1, const int tid) {
    const _Float16* __restrict__ S = (const _Float16*)(wst + OFF_B0);
    const float* __restrict__ inv = wst + OFF_INV;
    _Float16* __restrict__ Ph = (_Float16*)(wst + OFF_B1);
    const int c0 = tid * 4;
    const int h1 = l1 / WP, w1 = l1 % WP;
    float lg[4] = {-3.0e38f, -3.0e38f, -3.0e38f, -3.0e38f};
    float mx = -3.0e38f;
    if (tid < 248) {
        int hc[4], wc[4];
#pragma unroll
        for (int j = 0; j < 4; ++j) { hc[j] = (c0 + j) / WP; wc[j] = (c0 + j) % WP; }
        float g[4] = {0.f, 0.f, 0.f, 0.f};
        const _Float16* base = S + l1 * NL + c0;
#pragma unroll
        for (int dh = -1; dh <= 1; ++dh) {
            const bool oh1 = (unsigned)(h1 + dh) < (unsigned)HP;
#pragma unroll
            for (int dw = -1; dw <= 1; ++dw) {
                const int sh = dh * WP + dw;     // compile-time after unroll
                const int par = sh & 1;
                const bool ok1 = oh1 && (unsigned)(w1 + dw) < (unsigned)WP;
                const half8u v = *(const half8u*)(base + sh * (NL + 1) - par);
#pragma unroll
                for (int j = 0; j < 4; ++j) {
                    const bool ok = ok1 && (unsigned)(hc[j] + dh) < (unsigned)HP &&
                                           (unsigned)(wc[j] + dw) < (unsigned)WP;
                    if (ok) g[j] += (float)v[j + par];
                }
            }
        }
        const float inv1 = inv[l1] * 10.0f;
#pragma unroll
        for (int j = 0; j < 4; ++j) {
            lg[j] = g[j] * inv1 * inv[c0 + j];
            mx = fmaxf(mx, lg[j]);
        }
    }
    __shared__ float red[4];
    const int wave = tid >> 6, lane = tid & 63;
#pragma unroll
    for (int off = 32; off > 0; off >>= 1) mx = fmaxf(mx, __shfl_down(mx, off));
    if (lane == 0) red[wave] = mx;
    __syncthreads();
    mx = fmaxf(fmaxf(red[0], red[1]), fmaxf(red[2], red[3]));
    __syncthreads();
    float e[4];
    float sum = 0.0f;
#pragma unroll
    for (int j = 0; j < 4; ++j) { e[j] = __expf(lg[j] - mx); sum += e[j]; }
    if (tid >= 248) sum = 0.0f;
#pragma unroll
    for (int off = 32; off > 0; off >>= 1) sum += __shfl_down(sum, off);
    if (lane == 0) red[wave] = sum;
    __syncthreads();
    sum = red[0] + red[1] + red[2] + red[3];
    const float rs = 1.0f / sum;
    if (tid < 248) {
        half4h o;
#pragma unroll
        for (int j = 0; j < 4; ++j) o[j] = (_Float16)(e[j] * rs);
        *(half4u*)(Ph + l1 * NL + c0) = o;
    }
}

__global__ __launch_bounds__(256) void k_softmax9(float* __restrict__ ws) {
    const int t = blockIdx.x & 7;
    const int l1 = blockIdx.x >> 3;
    float* wst = ws + (size_t)t * TSTRIDE;
    if (t & 1) softmax9_body<31, 32>(wst, l1, threadIdx.x);
    else       softmax9_body<32, 31>(wst, l1, threadIdx.x);
}

// ---------------- K5: Wh = 9-pt band(Ph), B1 -> B0 ----------------
template<int WP, int HP>
__device__ __forceinline__ void band9p_body(float* __restrict__ wst,
                                            const int m, const int tid) {
    if (tid >= 248) return;
    const _Float16* __restrict__ P = (const _Float16*)(wst + OFF_B1);
    _Float16* __restrict__ W = (_Float16*)(wst + OFF_B0);
    const int c0 = tid * 4;
    const int hm = m / WP, wm = m % WP;
    int hc[4], wc[4];
#pragma unroll
    for (int j = 0; j < 4; ++j) { hc[j] = (c0 + j) / WP; wc[j] = (c0 + j) % WP; }
    float acc[4] = {0.f, 0.f, 0.f, 0.f};
    const _Float16* base = P + m * NL + c0;
#pragma unroll
    for (int dh = -1; dh <= 1; ++dh) {
        const bool oh1 = (unsigned)(hm + dh) < (unsigned)HP;
#pragma unroll
        for (int dw = -1; dw <= 1; ++dw) {
            const int sh = dh * WP + dw;
            const int par = sh & 1;
            const bool ok1 = oh1 && (unsigned)(wm + dw) < (unsigned)WP;
            const half8u v = *(const half8u*)(base + sh * (NL + 1) - par);
#pragma unroll
            for (int j = 0; j < 4; ++j) {
                const bool ok = ok1 && (unsigned)(hc[j] + dh) < (unsigned)HP &&
                                       (unsigned)(wc[j] + dw) < (unsigned)WP;
                if (ok) acc[j] += (float)v[j + par];
            }
        }
    }
    half4h o;
#pragma unroll
    for (int j = 0; j < 4; ++j) o[j] = (_Float16)acc[j];
    *(half4u*)(W + m * NL + c0) = o;
}

__global__ __launch_bounds__(256) void k_band9p(float* __restrict__ ws) {
    const int t = blockIdx.x & 7;
    const int m = blockIdx.x >> 3;
    float* wst = ws + (size_t)t * TSTRIDE;
    if (t & 1) band9p_body<31, 32>(wst, m, threadIdx.x);
    else       band9p_body<32, 31>(wst, m, threadIdx.x);
}

// ---------------- K6: Y = Wh @ ABt^T (992x512, K=992) MFMA f16 ----------------
__global__ __launch_bounds__(256) void k_recon(float* __restrict__ ws) {
    const int t = blockIdx.x & 7;
    const int u = blockIdx.x >> 3;    // 0..31 = 8 iy x 4 jx
    const int i0 = (u >> 2) * 128, j0 = (u & 3) * 128;
    float* wst = ws + (size_t)t * TSTRIDE;
    const _Float16* __restrict__ Wm = (const _Float16*)(wst + OFF_B0);
    const _Float16* __restrict__ ABt = (const _Float16*)(wst + OFF_ABT);
    float* __restrict__ Y = wst + OFF_Y;
    __shared__ __align__(16) _Float16 As[128 * 32];
    __shared__ __align__(16) _Float16 Bs[128 * 32];
    const int tid = threadIdx.x;
    const int wave = tid >> 6, lane = tid & 63;
    const int wm = wave & 1, wn = wave >> 1;
    const int l15 = lane & 15, quad = lane >> 4;
    floatx4 acc[4][4] = {};
    const int srow = tid >> 2;
    const int scol = (tid & 3) * 8;
    for (int k0 = 0; k0 < NL; k0 += 32) {   // 31 exact iterations
        __syncthreads();
        if (i0 + srow < NL)      gload16(&Wm[(i0 + srow) * NL + k0 + scol], &As[srow * 32 + scol]);
        if (i0 + 64 + srow < NL) gload16(&Wm[(i0 + 64 + srow) * NL + k0 + scol], &As[(64 + srow) * 32 + scol]);
        gload16(&ABt[(j0 + srow) * NL + k0 + scol], &Bs[srow * 32 + scol]);
        gload16(&ABt[(j0 + 64 + srow) * NL + k0 + scol], &Bs[(64 + srow) * 32 + scol]);
        __syncthreads();
        half8 a[4], b[4];
#pragma unroll
        for (int mt = 0; mt < 4; ++mt) a[mt] = *(const half8*)&As[(wm * 64 + mt * 16 + l15) * 32 + quad * 8];
#pragma unroll
        for (int nt = 0; nt < 4; ++nt) b[nt] = *(const half8*)&Bs[(wn * 64 + nt * 16 + l15) * 32 + quad * 8];
#pragma unroll
        for (int mt = 0; mt < 4; ++mt)
#pragma unroll
            for (int nt = 0; nt < 4; ++nt)
                acc[mt][nt] = __builtin_amdgcn_mfma_f32_16x16x32_f16(a[mt], b[nt], acc[mt][nt], 0, 0, 0);
    }
#pragma unroll
    for (int mt = 0; mt < 4; ++mt)
#pragma unroll
        for (int nt = 0; nt < 4; ++nt)
#pragma unroll
            for (int r = 0; r < 4; ++r) {
                const int row = i0 + wm * 64 + mt * 16 + quad * 4 + r;
                const int col = j0 + wn * 64 + nt * 16 + l15;
                if (row < NL) Y[row * NC2 + col] = acc[mt][nt][r];
            }
}

// ---------------- K7: seam combine -> out ----------------
__global__ __launch_bounds__(256) void k_combine(float* __restrict__ out,
                                                 const float* __restrict__ ws) {
    const int idx = blockIdx.x;          // s*1024 + h*32 + w
    const int s = idx >> 10;
    const int hw = idx & 1023;
    const int h = hw >> 5, w = hw & 31;
    const int c = threadIdx.x;
    const float* Ylr = ws + (size_t)(2 * s) * TSTRIDE + OFF_Y;
    const float* Ytb = ws + (size_t)(2 * s + 1) * TSTRIDE + OFF_Y;
    float v = 0.0f;
    if (h < 31) v += Ylr[(h * 32 + w) * NC2 + NC + c] * (h == 0 ? 1.0f : 0.5f);
    if (h >= 1) v += Ylr[((h - 1) * 32 + w) * NC2 + c] * (h == 31 ? 1.0f : 0.5f);
    if (w < 31) v += Ytb[(h * 31 + w) * NC2 + c] * (w == 0 ? 1.0f : 0.5f);
    if (w >= 1) v += Ytb[(h * 31 + (w - 1)) * NC2 + NC + c] * (w == 31 ? 1.0f : 0.5f);
    out[(size_t)idx * NC + c] = v * 0.5f;
}

extern "C" void kernel_launch(void* const* d_in, const int* in_sizes, int n_in,
                              void* d_out, int out_size, void* d_ws, size_t ws_size,
                              hipStream_t stream) {
    const float* x = (const float*)d_in[0];
    float* out = (float*)d_out;
    float* ws = (float*)d_ws;    // 8*TSTRIDE*4 = 60 MB used

    hipLaunchKernelGGL(k_stage,    dim3(8 * 31), dim3(256),  0, stream, x, ws);
    hipLaunchKernelGGL(k_inv,      dim3(8),      dim3(1024), 0, stream, ws);
    hipLaunchKernelGGL(k_gram,     dim3(8 * 64), dim3(256),  0, stream, ws);
    hipLaunchKernelGGL(k_softmax9, dim3(8 * NL), dim3(256),  0, stream, ws);
    hipLaunchKernelGGL(k_band9p,   dim3(8 * NL), dim3(256),  0, stream, ws);
    hipLaunchKernelGGL(k_recon,    dim3(8 * 32), dim3(256),  0, stream, ws);
    hipLaunchKernelGGL(k_combine,  dim3(4096),   dim3(256),  0, stream, out, ws);
}

// Round 7
// 146.093 us; speedup vs baseline: 1.3528x; 1.0225x over previous
//
#include <hip/hip_runtime.h>

// B=4, H=W=32, C=256. 8 tasks (sample x orientation), grid L=992 each.
// Pipeline (6 dispatches):
//   k_stage:    Mh=f16(a*b), ABt (transposed f16 a|b), per-pixel sq norms
//   k_gram:     S = Mh Mh^T (MFMA f16 -> B0), 64x64 tiles (8 blk/CU); u==0
//               blocks also compute inv (3x3 box sums of norms)
//   k_softmax9: G = 9-pt band(S) -> softmax -> Ph (B0->B1)
//   k_band9p:   Wh = 9-pt band(Ph)              (B1->B0)
//   k_recon:    Y(f16) = Wh @ ABt^T (MFMA f16), 64x64 tiles (4 blk/CU)
//   k_combine:  seam average -> out
// R6 lesson: 128x128 GEMM tiles ran at 1-2 blocks/CU (no latency hiding);
// 64x64 keeps the 512 B-staged/MFMA ratio but gives 4-8 blocks/CU.

typedef _Float16 half8 __attribute__((ext_vector_type(8)));
typedef _Float16 half8u __attribute__((ext_vector_type(8), aligned(4)));
typedef _Float16 half4h __attribute__((ext_vector_type(4)));
typedef _Float16 half4u __attribute__((ext_vector_type(4), aligned(8)));
typedef float floatx4 __attribute__((ext_vector_type(4)));

constexpr int NL = 992, NC = 256, NC2 = 512;
constexpr int NLL = NL * NL;
// float-granular per-task offsets. B0/B1 last: +-65KB stencil over/under-
// reads stay inside d_ws (ws is 256MB, we use 47.8MB).
constexpr int OFF_ABT = 0;                      // f16 [512][992]
constexpr int OFF_MH  = OFF_ABT + NL * NC2 / 2; // f16 [992][256]
constexpr int OFF_SA  = OFF_MH + NL * NC / 2;
constexpr int OFF_SB  = OFF_SA + 1024;
constexpr int OFF_INV = OFF_SA + 2048;
constexpr int OFF_Y   = OFF_SA + 3072;          // f16 [992][512]
constexpr int OFF_B0  = OFF_Y + NL * NC2 / 2;   // f16 LxL: S, later Wh
constexpr int OFF_B1  = OFF_B0 + NLL / 2;       // f16 LxL: Ph
constexpr int TSTRIDE = OFF_B1 + NLL / 2;       // 1,495,040 f -> 47.8 MB

__device__ __forceinline__ void gload16(const void* g, void* l) {
    __builtin_amdgcn_global_load_lds(
        (const __attribute__((address_space(1))) unsigned int*)g,
        (__attribute__((address_space(3))) unsigned int*)(unsigned long)(uintptr_t)l,
        16, 0, 0);
}

// ------- K1: one x-pass -> Mh, ABt (both halves), per-pixel sq norms -------
__global__ __launch_bounds__(256) void k_stage(const float* __restrict__ x,
                                               float* __restrict__ ws) {
    const int t = blockIdx.x & 7;
    const int l0 = (blockIdx.x >> 3) * 32;   // 31 l-blocks
    const int s = t >> 1, o = t & 1;
    float* wst = ws + (size_t)t * TSTRIDE;
    _Float16* __restrict__ ABt = (_Float16*)(wst + OFF_ABT);
    _Float16* __restrict__ Mh = (_Float16*)(wst + OFF_MH);
    __shared__ float Ta[32 * 33], Tb[32 * 33];
    const int tid = threadIdx.x;
    const int li = tid >> 3, cq = tid & 7;
    const int l = l0 + li;
    int aoff, boff;
    if (o == 0) {  // lr grid (31,32): a=x[s,lh,lw], b=x[s,lh+1,lw]
        const int lh = l >> 5, lw = l & 31;
        aoff = ((s * 32 + lh) * 32 + lw) * NC;
        boff = aoff + 32 * NC;
    } else {       // tb grid (32,31): a=x[s,lh,lw+1], b=x[s,lh,lw]
        const int lh = l / 31, lw = l - lh * 31;
        boff = ((s * 32 + lh) * 32 + lw) * NC;
        aoff = boff + NC;
    }
    float sa = 0.0f, sb = 0.0f;
    for (int cc = 0; cc < 8; ++cc) {
        const int c0 = cc * 32;
        const float4 a4 = *(const float4*)&x[aoff + c0 + cq * 4];
        const float4 b4 = *(const float4*)&x[boff + c0 + cq * 4];
        half4h m;
        m[0] = (_Float16)(a4.x * b4.x); m[1] = (_Float16)(a4.y * b4.y);
        m[2] = (_Float16)(a4.z * b4.z); m[3] = (_Float16)(a4.w * b4.w);
        *(half4u*)&Mh[l * NC + c0 + cq * 4] = m;
        sa += a4.x * a4.x + a4.y * a4.y + a4.z * a4.z + a4.w * a4.w;
        sb += b4.x * b4.x + b4.y * b4.y + b4.z * b4.z + b4.w * b4.w;
        __syncthreads();   // guard previous iteration's LDS reads
        Ta[(cq * 4 + 0) * 33 + li] = a4.x; Tb[(cq * 4 + 0) * 33 + li] = b4.x;
        Ta[(cq * 4 + 1) * 33 + li] = a4.y; Tb[(cq * 4 + 1) * 33 + li] = b4.y;
        Ta[(cq * 4 + 2) * 33 + li] = a4.z; Tb[(cq * 4 + 2) * 33 + li] = b4.z;
        Ta[(cq * 4 + 3) * 33 + li] = a4.w; Tb[(cq * 4 + 3) * 33 + li] = b4.w;
        __syncthreads();
        const int ci = li, lq = cq;
        half4h ha, hb;
#pragma unroll
        for (int j = 0; j < 4; ++j) {
            ha[j] = (_Float16)Ta[ci * 33 + lq * 4 + j];
            hb[j] = (_Float16)Tb[ci * 33 + lq * 4 + j];
        }
        *(half4u*)&ABt[(c0 + ci) * NL + l0 + lq * 4] = ha;
        *(half4u*)&ABt[(NC + c0 + ci) * NL + l0 + lq * 4] = hb;
    }
#pragma unroll
    for (int off = 4; off > 0; off >>= 1) {
        sa += __shfl_down(sa, off, 8);
        sb += __shfl_down(sb, off, 8);
    }
    if (cq == 0) {
        wst[OFF_SA + l] = sa;
        wst[OFF_SB + l] = sb;
    }
}

// -------- K2: S = Mh Mh^T, 64x64 tile, BK=64; u==0 blocks also do inv -------
__global__ __launch_bounds__(256) void k_gram(float* __restrict__ ws) {
    const int t = blockIdx.x & 7;
    const int u = blockIdx.x >> 3;    // 0..255 = 16 iy x 16 jx
    const int i0 = (u >> 4) * 64, j0 = (u & 15) * 64;
    float* wst = ws + (size_t)t * TSTRIDE;
    const _Float16* __restrict__ M = (const _Float16*)(wst + OFF_MH);
    _Float16* __restrict__ S = (_Float16*)(wst + OFF_B0);
    const int tid = threadIdx.x;

    if (u == 0) {  // fused inv: 3x3 box sums of sq norms -> 1/(max*max)
        const int o = t & 1;
        const int Hp = o ? 32 : 31, Wp = o ? 31 : 32;
#pragma unroll
        for (int q = 0; q < 4; ++q) {
            const int l = tid + q * 256;
            if (l < NL) {
                const int h = l / Wp, w = l - h * Wp;
                float na2 = 0.0f, nb2 = 0.0f;
#pragma unroll
                for (int dh = -1; dh <= 1; ++dh)
#pragma unroll
                    for (int dw = -1; dw <= 1; ++dw) {
                        const int hh = h + dh, ww = w + dw;
                        if ((unsigned)hh < (unsigned)Hp && (unsigned)ww < (unsigned)Wp) {
                            const int ll = hh * Wp + ww;
                            na2 += wst[OFF_SA + ll];
                            nb2 += wst[OFF_SB + ll];
                        }
                    }
                const float na = fmaxf(sqrtf(na2), 1e-4f);
                const float nb = fmaxf(sqrtf(nb2), 1e-4f);
                wst[OFF_INV + l] = 1.0f / (na * nb);
            }
        }
    }

    __shared__ __align__(16) _Float16 As[64 * 64];
    __shared__ __align__(16) _Float16 Bs[64 * 64];
    const int wave = tid >> 6, lane = tid & 63;
    const int wm = wave & 1, wn = wave >> 1;
    const int l15 = lane & 15, quad = lane >> 4;
    floatx4 acc[2][2] = {};
    for (int k0 = 0; k0 < NC; k0 += 64) {   // 4 iters
        __syncthreads();
#pragma unroll
        for (int rr = 0; rr < 2; ++rr) {
            const int slot = tid + rr * 256;
            const int row = slot >> 3, cg = (slot & 7) * 8;
            if (i0 + row < NL) gload16(&M[(i0 + row) * NC + k0 + cg], &As[row * 64 + cg]);
            if (j0 + row < NL) gload16(&M[(j0 + row) * NC + k0 + cg], &Bs[row * 64 + cg]);
        }
        __syncthreads();
#pragma unroll
        for (int kk = 0; kk < 2; ++kk) {
            half8 a[2], b[2];
#pragma unroll
            for (int mt = 0; mt < 2; ++mt) a[mt] = *(const half8*)&As[(wm * 32 + mt * 16 + l15) * 64 + kk * 32 + quad * 8];
#pragma unroll
            for (int nt = 0; nt < 2; ++nt) b[nt] = *(const half8*)&Bs[(wn * 32 + nt * 16 + l15) * 64 + kk * 32 + quad * 8];
#pragma unroll
            for (int mt = 0; mt < 2; ++mt)
#pragma unroll
                for (int nt = 0; nt < 2; ++nt)
                    acc[mt][nt] = __builtin_amdgcn_mfma_f32_16x16x32_f16(a[mt], b[nt], acc[mt][nt], 0, 0, 0);
        }
    }
#pragma unroll
    for (int mt = 0; mt < 2; ++mt)
#pragma unroll
        for (int nt = 0; nt < 2; ++nt)
#pragma unroll
            for (int r = 0; r < 4; ++r) {
                const int row = i0 + wm * 32 + mt * 16 + quad * 4 + r;
                const int col = j0 + wn * 32 + nt * 16 + l15;
                if (row < NL && col < NL) S[row * NL + col] = (_Float16)acc[mt][nt][r];
            }
}

// -------- K3: G = 9-pt band(S) fused -> softmax -> Ph, B0 -> B1 --------
template<int WP, int HP>
__device__ __forceinline__ void softmax9_body(float* __restrict__ wst,
                                              const int l1, const int tid) {
    const _Float16* __restrict__ S = (const _Float16*)(wst + OFF_B0);
    const float* __restrict__ inv = wst + OFF_INV;
    _Float16* __restrict__ Ph = (_Float16*)(wst + OFF_B1);
    const int c0 = tid * 4;
    const int h1 = l1 / WP, w1 = l1 % WP;
    float lg[4] = {-3.0e38f, -3.0e38f, -3.0e38f, -3.0e38f};
    float mx = -3.0e38f;
    if (tid < 248) {
        int hc[4], wc[4];
#pragma unroll
        for (int j = 0; j < 4; ++j) { hc[j] = (c0 + j) / WP; wc[j] = (c0 + j) % WP; }
        float g[4] = {0.f, 0.f, 0.f, 0.f};
        const _Float16* base = S + l1 * NL + c0;
#pragma unroll
        for (int dh = -1; dh <= 1; ++dh) {
            const bool oh1 = (unsigned)(h1 + dh) < (unsigned)HP;
#pragma unroll
            for (int dw = -1; dw <= 1; ++dw) {
                const int sh = dh * WP + dw;     // compile-time after unroll
                const int par = sh & 1;
                const bool ok1 = oh1 && (unsigned)(w1 + dw) < (unsigned)WP;
                const half8u v = *(const half8u*)(base + sh * (NL + 1) - par);
#pragma unroll
                for (int j = 0; j < 4; ++j) {
                    const bool ok = ok1 && (unsigned)(hc[j] + dh) < (unsigned)HP &&
                                           (unsigned)(wc[j] + dw) < (unsigned)WP;
                    if (ok) g[j] += (float)v[j + par];
                }
            }
        }
        const float inv1 = inv[l1] * 10.0f;
#pragma unroll
        for (int j = 0; j < 4; ++j) {
            lg[j] = g[j] * inv1 * inv[c0 + j];
            mx = fmaxf(mx, lg[j]);
        }
    }
    __shared__ float red[4];
    const int wave = tid >> 6, lane = tid & 63;
#pragma unroll
    for (int off = 32; off > 0; off >>= 1) mx = fmaxf(mx, __shfl_down(mx, off));
    if (lane == 0) red[wave] = mx;
    __syncthreads();
    mx = fmaxf(fmaxf(red[0], red[1]), fmaxf(red[2], red[3]));
    __syncthreads();
    float e[4];
    float sum = 0.0f;
#pragma unroll
    for (int j = 0; j < 4; ++j) { e[j] = __expf(lg[j] - mx); sum += e[j]; }
    if (tid >= 248) sum = 0.0f;
#pragma unroll
    for (int off = 32; off > 0; off >>= 1) sum += __shfl_down(sum, off);
    if (lane == 0) red[wave] = sum;
    __syncthreads();
    sum = red[0] + red[1] + red[2] + red[3];
    const float rs = 1.0f / sum;
    if (tid < 248) {
        half4h o;
#pragma unroll
        for (int j = 0; j < 4; ++j) o[j] = (_Float16)(e[j] * rs);
        *(half4u*)(Ph + l1 * NL + c0) = o;
    }
}

__global__ __launch_bounds__(256) void k_softmax9(float* __restrict__ ws) {
    const int t = blockIdx.x & 7;
    const int l1 = blockIdx.x >> 3;
    float* wst = ws + (size_t)t * TSTRIDE;
    if (t & 1) softmax9_body<31, 32>(wst, l1, threadIdx.x);
    else       softmax9_body<32, 31>(wst, l1, threadIdx.x);
}

// ---------------- K4: Wh = 9-pt band(Ph), B1 -> B0 ----------------
template<int WP, int HP>
__device__ __forceinline__ void band9p_body(float* __restrict__ wst,
                                            const int m, const int tid) {
    if (tid >= 248) return;
    const _Float16* __restrict__ P = (const _Float16*)(wst + OFF_B1);
    _Float16* __restrict__ W = (_Float16*)(wst + OFF_B0);
    const int c0 = tid * 4;
    const int hm = m / WP, wm = m % WP;
    int hc[4], wc[4];
#pragma unroll
    for (int j = 0; j < 4; ++j) { hc[j] = (c0 + j) / WP; wc[j] = (c0 + j) % WP; }
    float acc[4] = {0.f, 0.f, 0.f, 0.f};
    const _Float16* base = P + m * NL + c0;
#pragma unroll
    for (int dh = -1; dh <= 1; ++dh) {
        const bool oh1 = (unsigned)(hm + dh) < (unsigned)HP;
#pragma unroll
        for (int dw = -1; dw <= 1; ++dw) {
            const int sh = dh * WP + dw;
            const int par = sh & 1;
            const bool ok1 = oh1 && (unsigned)(wm + dw) < (unsigned)WP;
            const half8u v = *(const half8u*)(base + sh * (NL + 1) - par);
#pragma unroll
            for (int j = 0; j < 4; ++j) {
                const bool ok = ok1 && (unsigned)(hc[j] + dh) < (unsigned)HP &&
                                       (unsigned)(wc[j] + dw) < (unsigned)WP;
                if (ok) acc[j] += (float)v[j + par];
            }
        }
    }
    half4h o;
#pragma unroll
    for (int j = 0; j < 4; ++j) o[j] = (_Float16)acc[j];
    *(half4u*)(W + m * NL + c0) = o;
}

__global__ __launch_bounds__(256) void k_band9p(float* __restrict__ ws) {
    const int t = blockIdx.x & 7;
    const int m = blockIdx.x >> 3;
    float* wst = ws + (size_t)t * TSTRIDE;
    if (t & 1) band9p_body<31, 32>(wst, m, threadIdx.x);
    else       band9p_body<32, 31>(wst, m, threadIdx.x);
}

// -------- K5: Y(f16) = Wh @ ABt^T, 64x64 tile, BK=32, 31 exact iters -------
__global__ __launch_bounds__(256) void k_recon(float* __restrict__ ws) {
    const int t = blockIdx.x & 7;
    const int u = blockIdx.x >> 3;    // 0..127 = 16 iy x 8 jx
    const int i0 = (u >> 3) * 64, j0 = (u & 7) * 64;
    float* wst = ws + (size_t)t * TSTRIDE;
    const _Float16* __restrict__ Wm = (const _Float16*)(wst + OFF_B0);
    const _Float16* __restrict__ ABt = (const _Float16*)(wst + OFF_ABT);
    _Float16* __restrict__ Y = (_Float16*)(wst + OFF_Y);
    __shared__ __align__(16) _Float16 As[64 * 32];
    __shared__ __align__(16) _Float16 Bs[64 * 32];
    const int tid = threadIdx.x;
    const int wave = tid >> 6, lane = tid & 63;
    const int wm = wave & 1, wn = wave >> 1;
    const int l15 = lane & 15, quad = lane >> 4;
    floatx4 acc[2][2] = {};
    const int row = tid >> 2, cg = (tid & 3) * 8;
    for (int k0 = 0; k0 < NL; k0 += 32) {   // 31 exact iterations
        __syncthreads();
        if (i0 + row < NL) gload16(&Wm[(i0 + row) * NL + k0 + cg], &As[row * 32 + cg]);
        gload16(&ABt[(j0 + row) * NL + k0 + cg], &Bs[row * 32 + cg]);
        __syncthreads();
        half8 a[2], b[2];
#pragma unroll
        for (int mt = 0; mt < 2; ++mt) a[mt] = *(const half8*)&As[(wm * 32 + mt * 16 + l15) * 32 + quad * 8];
#pragma unroll
        for (int nt = 0; nt < 2; ++nt) b[nt] = *(const half8*)&Bs[(wn * 32 + nt * 16 + l15) * 32 + quad * 8];
#pragma unroll
        for (int mt = 0; mt < 2; ++mt)
#pragma unroll
            for (int nt = 0; nt < 2; ++nt)
                acc[mt][nt] = __builtin_amdgcn_mfma_f32_16x16x32_f16(a[mt], b[nt], acc[mt][nt], 0, 0, 0);
    }
#pragma unroll
    for (int mt = 0; mt < 2; ++mt)
#pragma unroll
        for (int nt = 0; nt < 2; ++nt)
#pragma unroll
            for (int r = 0; r < 4; ++r) {
                const int rw = i0 + wm * 32 + mt * 16 + quad * 4 + r;
                const int col = j0 + wn * 32 + nt * 16 + l15;
                if (rw < NL) Y[rw * NC2 + col] = (_Float16)acc[mt][nt][r];
            }
}

// ---------------- K6: seam combine -> out ----------------
__global__ __launch_bounds__(256) void k_combine(float* __restrict__ out,
                                                 const float* __restrict__ ws) {
    const int idx = blockIdx.x;          // s*1024 + h*32 + w
    const int s = idx >> 10;
    const int hw = idx & 1023;
    const int h = hw >> 5, w = hw & 31;
    const int c = threadIdx.x;
    const _Float16* Ylr = (const _Float16*)(ws + (size_t)(2 * s) * TSTRIDE + OFF_Y);
    const _Float16* Ytb = (const _Float16*)(ws + (size_t)(2 * s + 1) * TSTRIDE + OFF_Y);
    float v = 0.0f;
    if (h < 31) v += (float)Ylr[(h * 32 + w) * NC2 + NC + c] * (h == 0 ? 1.0f : 0.5f);
    if (h >= 1) v += (float)Ylr[((h - 1) * 32 + w) * NC2 + c] * (h == 31 ? 1.0f : 0.5f);
    if (w < 31) v += (float)Ytb[(h * 31 + w) * NC2 + c] * (w == 0 ? 1.0f : 0.5f);
    if (w >= 1) v += (float)Ytb[(h * 31 + (w - 1)) * NC2 + NC + c] * (w == 31 ? 1.0f : 0.5f);
    out[(size_t)idx * NC + c] = v * 0.5f;
}

extern "C" void kernel_launch(void* const* d_in, const int* in_sizes, int n_in,
                              void* d_out, int out_size, void* d_ws, size_t ws_size,
                              hipStream_t stream) {
    const float* x = (const float*)d_in[0];
    float* out = (float*)d_out;
    float* ws = (float*)d_ws;    // 8*TSTRIDE*4 = 47.8 MB used

    hipLaunchKernelGGL(k_stage,    dim3(8 * 31),  dim3(256), 0, stream, x, ws);
    hipLaunchKernelGGL(k_gram,     dim3(8 * 256), dim3(256), 0, stream, ws);
    hipLaunchKernelGGL(k_softmax9, dim3(8 * NL),  dim3(256), 0, stream, ws);
    hipLaunchKernelGGL(k_band9p,   dim3(8 * NL),  dim3(256), 0, stream, ws);
    hipLaunchKernelGGL(k_recon,    dim3(8 * 128), dim3(256), 0, stream, ws);
    hipLaunchKernelGGL(k_combine,  dim3(4096),    dim3(256), 0, stream, out, ws);
}